// Round 13
// baseline (318.549 us; speedup 1.0000x reference)
//
#include <hip/hip_runtime.h>
#include <hip/hip_bf16.h>

// FactorAtt (CoaT) fused pipeline v12, MI355X/gfx950.
// B=8, N=4096, C=768, H=12, D=64.  M_tot = B*N = 32768.
//
// Math: out[b] = q[b] @ M[b] + bp, where
//   Kh = k @ Wk^T (bf16), Vh = v @ Wv^T
//   ctx[b,h,dk,dv] = sum_n softmax_n(Kh)[n,dk] * Vh[n,dv]
//   Gt[b][co][h*64+dk] = sum_dv ctx[b,h,dk,dv] * Wp[co, h*64+dv]
//   Mt[b][co][ci] = sum_kk Gt[b][co][kk] * Wq[kk][ci]
//   out[b][n,co] = sum_ci q[b][n,ci] * Mt[b][co,ci] + bp[co]
// v12 = v10 (best, 299.7us) with final GEMM split: cast q -> bf16 GEMM
// (measured: fused-AF32 final ~155us vs split 24+109=133).  Proj stays
// fused-AF32 (155 ~= split 157, one less dispatch).  v11's reg-staging
// reverted (regressed: vmcnt drain serialized before ds_write).

typedef __bf16 bf16x8 __attribute__((ext_vector_type(8)));
typedef __bf16 bf16x4 __attribute__((ext_vector_type(4)));
typedef float f32x4 __attribute__((ext_vector_type(4)));

#define GLOAD_LDS16(g, l)                                                        \
  __builtin_amdgcn_global_load_lds(                                              \
      (const __attribute__((address_space(1))) void*)(g),                        \
      (__attribute__((address_space(3))) void*)(l), 16, 0, 0)

__device__ __forceinline__ float bf2f(__hip_bfloat16 h) { return __bfloat162float(h); }

// ---------------------------------------------------------------- casts
// y-indexed multi-tensor cast: y=0 Wk, y=1 Wv (WE each); y=2.. : q (XE, 64 chunks)
__global__ void cast_kernel(const float* __restrict__ src,
                            __bf16* __restrict__ dst, long n) {
  long i = ((long)blockIdx.x * blockDim.x + threadIdx.x) * 4;
  if (i + 3 < n) {
    const float4 f = *(const float4*)(src + i);
    bf16x4 u = {(__bf16)f.x, (__bf16)f.y, (__bf16)f.z, (__bf16)f.w};
    *(bf16x4*)(dst + i) = u;
  }
}

__global__ void cast2_kernel(const float* __restrict__ s0, const float* __restrict__ s1,
                             __bf16* __restrict__ d0, __bf16* __restrict__ d1) {
  const float* src = blockIdx.y == 0 ? s0 : s1;
  __bf16* dst = blockIdx.y == 0 ? d0 : d1;
  const long i = ((long)blockIdx.x * blockDim.x + threadIdx.x) * 4;
  const float4 f = *(const float4*)(src + i);
  bf16x4 u = {(__bf16)f.x, (__bf16)f.y, (__bf16)f.z, (__bf16)f.w};
  *(bf16x4*)(dst + i) = u;
}

// dst[ci][kk] = src[kk][ci]  (768x768, fp32 -> bf16)
__global__ void transpose_cast(const float* __restrict__ src,
                               __bf16* __restrict__ dst) {
  __shared__ float tile[32][33];
  const int bx = blockIdx.x * 32, by = blockIdx.y * 32;
  const int tx = threadIdx.x, ty = threadIdx.y;  // 32 x 8
#pragma unroll
  for (int j = 0; j < 32; j += 8)
    tile[ty + j][tx] = src[(long)(bx + ty + j) * 768 + by + tx];
  __syncthreads();
#pragma unroll
  for (int j = 0; j < 32; j += 8)
    dst[(long)(by + ty + j) * 768 + bx + tx] = (__bf16)tile[tx][ty + j];
}

// ---------------------------------------------------------------- GEMM (B^T form)
// out[m,n] = sum_k A[m,k] * Bt[n,k];  K=768, tiles 128x128, BK=64, 4 waves.
// v7 structure: single-buffered LDS, 2 barriers per K-step, 12 K-steps.
// AF32 (v10): A fp32 in global via global_load_lds; LDS A = [128][64] f32,
//   16B-chunk swizzle phys = logical ^ (row&15); cast to bf16 at frag build.
// bf16: LDS A = [128][64] bf16, 8-chunk swizzle phys = logical ^ (row&7).
// A2 != nullptr: z==1 selects A2 (z-stride disabled).
template <bool AF32>
__global__ __launch_bounds__(256, 2)
void gemm_bt(const void* __restrict__ Abase_, const void* __restrict__ A2,
             const __bf16* __restrict__ Btbase,
             __bf16* __restrict__ outBbase,
             float* __restrict__ outF,
             const float* __restrict__ bias,
             long sAz, long sBz, long sOz, long sBbatch) {
  constexpr int K = 768;
  const int tid = threadIdx.x;
  const int lane = tid & 63;
  const int w = tid >> 6;
  const int wr = (w >> 1) * 64;
  const int wc = (w & 1) * 64;

  // bijective XCD-chunked swizzle (m204)
  long flat = ((long)blockIdx.z * gridDim.y + blockIdx.y) * gridDim.x + blockIdx.x;
  const long total = (long)gridDim.x * gridDim.y * gridDim.z;
  if ((total & 7) == 0) {
    flat = (flat & 7) * (total >> 3) + (flat >> 3);
  }
  const int bx = (int)(flat % gridDim.x);
  const long rem = flat / gridDim.x;
  const int by = (int)(rem % gridDim.y);
  const int bz = (int)(rem / gridDim.y);

  const int z = bz;
  const int m0 = by * 128;
  const int n0 = bx * 128;

  const __bf16* Bt = Btbase + (long)z * sBz + (long)(m0 >> 12) * sBbatch;

  __shared__ __align__(16) float AsF[AF32 ? 128 * 64 : 8];   // 32 KB (AF32)
  __shared__ __align__(16) __bf16 AsB[AF32 ? 8 : 128 * 64];  // 16 KB (bf16)
  __shared__ __align__(16) __bf16 Bs[128 * 64];              // 16 KB

  f32x4 acc[4][4] = {};

  // ---- B staging: issue p rows p*32 + w*8 + ro; chunk (lane&7)^ro
  const int ro = lane >> 3;
  const int gck = (lane & 7) ^ ro;
  const __bf16* gB = Bt + (long)(n0 + w * 8 + ro) * K + gck * 8;

  // ---- A staging
  const void* Asel = (A2 != nullptr && z == 1) ? A2 : Abase_;
  const long az = (A2 == nullptr) ? (long)z * sAz : 0;
  const float* gAf = nullptr;
  const __bf16* gAb = nullptr;
  if constexpr (AF32) {
    // 8 issues; issue p rows p*16 + (tid>>4); logical chunk (tid&15)^(tid>>4)
    const int arow = tid >> 4;
    const int ach = (tid & 15) ^ arow;
    gAf = (const float*)Asel + az + (long)(m0 + arow) * K + ach * 4;
  } else {
    gAb = (const __bf16*)Asel + az + (long)(m0 + w * 8 + ro) * K + gck * 8;
  }

  const int rsel = lane & 15;
  const int r7 = rsel & 7;
  const int cseg = lane >> 4;  // 0..3

  for (int k0 = 0; k0 < K; k0 += 64) {
    if constexpr (AF32) {
#pragma unroll
      for (int p = 0; p < 8; ++p)
        GLOAD_LDS16(gAf + k0 + (long)p * 16 * K, &AsF[p * 1024 + w * 256]);
#pragma unroll
      for (int p = 0; p < 4; ++p)
        GLOAD_LDS16(gB + k0 + (long)p * 32 * K, &Bs[(p * 32 + w * 8) * 64]);
    } else {
#pragma unroll
      for (int p = 0; p < 4; ++p) {
        GLOAD_LDS16(gAb + k0 + (long)p * 32 * K, &AsB[(p * 32 + w * 8) * 64]);
        GLOAD_LDS16(gB + k0 + (long)p * 32 * K, &Bs[(p * 32 + w * 8) * 64]);
      }
    }
    __syncthreads();

#pragma unroll
    for (int kk = 0; kk < 2; ++kk) {
      bf16x8 af[4], bfr[4];
#pragma unroll
      for (int i = 0; i < 4; ++i) {
        const int rowa = wr + i * 16 + rsel;   // rowa & 15 == rsel
        const int rowb = wc + i * 16 + rsel;
        if constexpr (AF32) {
          const int c0 = kk * 8 + cseg * 2;    // logical f32-chunk (even)
          const f32x4 lo = *(const f32x4*)&AsF[rowa * 64 + ((c0 ^ rsel) << 2)];
          const f32x4 hi = *(const f32x4*)&AsF[rowa * 64 + (((c0 + 1) ^ rsel) << 2)];
          bf16x8 a = {(__bf16)lo[0], (__bf16)lo[1], (__bf16)lo[2], (__bf16)lo[3],
                      (__bf16)hi[0], (__bf16)hi[1], (__bf16)hi[2], (__bf16)hi[3]};
          af[i] = a;
        } else {
          const int ckl = kk * 4 + cseg;       // logical bf16-chunk
          af[i] = *(const bf16x8*)&AsB[rowa * 64 + ((ckl ^ r7) << 3)];
        }
        const int ckl = kk * 4 + cseg;
        bfr[i] = *(const bf16x8*)&Bs[rowb * 64 + ((ckl ^ r7) << 3)];
      }
#pragma unroll
      for (int i = 0; i < 4; ++i)
#pragma unroll
        for (int j = 0; j < 4; ++j)
          acc[i][j] = __builtin_amdgcn_mfma_f32_16x16x32_bf16(af[i], bfr[j], acc[i][j], 0, 0, 0);
    }
    __syncthreads();
  }

  // C/D layout (m89): col = lane&15, row = (lane>>4)*4 + r
  const int r0 = (lane >> 4) * 4;
  if (outF == nullptr) {
    __bf16* outp = outBbase + (long)z * sOz;
#pragma unroll
    for (int i = 0; i < 4; ++i) {
      const int row = m0 + wr + i * 16 + r0;
#pragma unroll
      for (int j = 0; j < 4; ++j) {
        const int col = n0 + wc + j * 16 + rsel;
#pragma unroll
        for (int r = 0; r < 4; ++r)
          outp[(long)(row + r) * 768 + col] = (__bf16)acc[i][j][r];
      }
    }
  } else {
#pragma unroll
    for (int i = 0; i < 4; ++i) {
      const int row = m0 + wr + i * 16 + r0;
#pragma unroll
      for (int j = 0; j < 4; ++j) {
        const int col = n0 + wc + j * 16 + rsel;
        const float bv = bias[col];
#pragma unroll
        for (int r = 0; r < 4; ++r)
          outF[(long)(row + r) * 768 + col] = acc[i][j][r] + bv;
      }
    }
  }
}

// ---------------------------------------------------------------- ctx partials
// Per (b,h), n-chunk of 512: U[dk,dv] += exp(Kh[n,dk]) * Vh[n,dv]; S[dk] += exp.
__global__ __launch_bounds__(256)
void ctx_partial(const __bf16* __restrict__ Kh,
                 const __bf16* __restrict__ Vh,
                 float* __restrict__ Upart, float* __restrict__ Spart) {
  const int bh = blockIdx.y, chunk = blockIdx.x;
  const int b = bh / 12, h = bh % 12;
  const int t = threadIdx.x;
  const int tdk = (t & 15) * 4, tdv = (t >> 4) * 4;
  const int sr = t >> 3, sc = (t & 7) * 8;
  __shared__ float ek[32][64];
  __shared__ float vv[32][64];
  f32x4 U[4] = {};
  float sacc = 0.f;
  const long base = ((long)b * 4096 + (long)chunk * 512) * 768 + h * 64;
#pragma unroll 1
  for (int it = 0; it < 16; ++it) {
    const long roff = base + (long)(it * 32 + sr) * 768 + sc;
    const bf16x8 kb = *(const bf16x8*)(Kh + roff);
    const bf16x8 vb = *(const bf16x8*)(Vh + roff);
    __syncthreads();
#pragma unroll
    for (int j = 0; j < 8; ++j) {
      ek[sr][sc + j] = __expf((float)kb[j]);
      vv[sr][sc + j] = (float)vb[j];
    }
    __syncthreads();
#pragma unroll 4
    for (int r = 0; r < 32; ++r) {
      const f32x4 a = *(const f32x4*)&ek[r][tdk];
      const f32x4 vx = *(const f32x4*)&vv[r][tdv];
      U[0] += a[0] * vx;
      U[1] += a[1] * vx;
      U[2] += a[2] * vx;
      U[3] += a[3] * vx;
    }
    if (t < 64) {
#pragma unroll 4
      for (int r = 0; r < 32; ++r) sacc += ek[r][t];
    }
  }
  float* Ub = Upart + (long)(bh * 8 + chunk) * 4096;
#pragma unroll
  for (int i = 0; i < 4; ++i) *(f32x4*)&Ub[(tdk + i) * 64 + tdv] = U[i];
  if (t < 64) Spart[(long)(bh * 8 + chunk) * 64 + t] = sacc;
}

__global__ __launch_bounds__(256)
void ctx_reduce(const float* __restrict__ Upart, const float* __restrict__ Spart,
                float* __restrict__ ctx) {
  const int bh = blockIdx.x;
  const int t = threadIdx.x;
  const int tdk = (t & 15) * 4, tdv = (t >> 4) * 4;
  __shared__ float S[64];
  if (t < 64) {
    float s = 0.f;
#pragma unroll
    for (int c = 0; c < 8; ++c) s += Spart[(long)(bh * 8 + c) * 64 + t];
    S[t] = s;
  }
  __syncthreads();
#pragma unroll
  for (int i = 0; i < 4; ++i) {
    const int dk = tdk + i;
    f32x4 u = {};
#pragma unroll
    for (int c = 0; c < 8; ++c)
      u += *(const f32x4*)&Upart[(long)(bh * 8 + c) * 4096 + dk * 64 + tdv];
    u *= (1.f / S[dk]);
    *(f32x4*)&ctx[(long)bh * 4096 + dk * 64 + tdv] = u;
  }
}

// ---------------------------------------------------------------- G matrix
// Gt[b][co][h*64+dk] = sum_dv ctx[b,h,dk,dv] * Wp[co, h*64+dv]   (bf16 out)
__global__ __launch_bounds__(256, 2)
void gstack(const float* __restrict__ ctx, const float* __restrict__ Wp,
            __bf16* __restrict__ Gt) {
  const int cc = blockIdx.x, h = blockIdx.y, b = blockIdx.z;
  const int t = threadIdx.x, lane = t & 63, w = t >> 6;
  const int co0 = cc * 192;
  __shared__ __align__(16) float wf[192 * 64];  // 48 KB

#pragma unroll
  for (int i = 0; i < 12; ++i) {
    const int flat = i * 256 + t;
    const int r = flat >> 4, c4 = flat & 15;
    const f32x4 vsrc = *(const f32x4*)&Wp[(long)(co0 + r) * 768 + h * 64 + c4 * 4];
    *(f32x4*)&wf[r * 64 + c4 * 4] = vsrc;
  }

  f32x4 cx[16];
  const float* crow = ctx + ((long)(b * 12 + h) * 64 + lane) * 64;
#pragma unroll
  for (int j = 0; j < 16; ++j) cx[j] = *(const f32x4*)&crow[j * 4];

  __syncthreads();

  __bf16* gout = Gt + ((long)(b * 768 + co0 + w * 48) * 768) + h * 64 + lane;
  for (int co = 0; co < 48; ++co) {
    const float* wrow = &wf[(w * 48 + co) * 64];
    f32x4 acc = {};
#pragma unroll
    for (int j = 0; j < 16; ++j) acc += cx[j] * *(const f32x4*)&wrow[j * 4];
    const float s = acc[0] + acc[1] + acc[2] + acc[3];
    gout[(long)co * 768] = (__bf16)s;
  }
}

// ---------------------------------------------------------------- launch
extern "C" void kernel_launch(void* const* d_in, const int* in_sizes, int n_in,
                              void* d_out, int out_size, void* d_ws, size_t ws_size,
                              hipStream_t stream) {
  (void)in_sizes; (void)n_in; (void)out_size; (void)ws_size;
  const float* q = (const float*)d_in[0];
  const float* k = (const float*)d_in[1];
  const float* v = (const float*)d_in[2];
  const float* Wq = (const float*)d_in[3];
  const float* Wk = (const float*)d_in[4];
  const float* Wv = (const float*)d_in[5];
  const float* Wp = (const float*)d_in[6];
  const float* bp = (const float*)d_in[7];
  float* out = (float*)d_out;

  const long XE = 32768L * 768L;
  const long WE = 768L * 768L;

  char* ws = (char*)d_ws;
  __bf16* Khb = (__bf16*)ws;                             // XE bf16
  __bf16* Vhb = Khb + XE;                                // XE bf16
  __bf16* Qb = Vhb + XE;                                 // XE bf16 (cast q)
  __bf16* Wb = Qb + XE;                                  // 4*WE bf16: Wk,Wv,(spare),WqT
  __bf16* Gt = Wb + 4 * WE;                              // 8*WE bf16
  __bf16* Mt = Gt + 8 * WE;                              // 8*WE bf16
  float* Upart = (float*)(Mt + 8 * WE);                  // 96*8*4096 f32
  float* Spart = Upart + 96L * 8 * 4096;                 // 96*8*64 f32
  float* ctx = Spart + 96L * 8 * 64;                     // 96*4096 f32

  // 1) weight casts (merged) + WqT + q cast (final GEMM uses bf16 A)
  cast2_kernel<<<dim3(576, 2), 256, 0, stream>>>(Wk, Wv, Wb + 0 * WE, Wb + 1 * WE);
  transpose_cast<<<dim3(24, 24), dim3(32, 8), 0, stream>>>(Wq, Wb + 3 * WE);  // WqT
  cast_kernel<<<24576, 256, 0, stream>>>(q, Qb, XE);

  // 2) K/V projections (z=2, fp32 A direct): z=0 Kh = k@Wk^T, z=1 Vh = v@Wv^T
  gemm_bt<true><<<dim3(6, 256, 2), 256, 0, stream>>>(k, v, Wb, Khb, nullptr,
                                                     nullptr, 0, WE, XE, 0);

  // 3) softmax-weighted context
  ctx_partial<<<dim3(8, 96), 256, 0, stream>>>(Khb, Vhb, Upart, Spart);
  ctx_reduce<<<96, 256, 0, stream>>>(Upart, Spart, ctx);

  // 4) Gt[b] = (ctx @ Wp-blocks)^T  (fp32 Wp direct)
  gstack<<<dim3(4, 12, 8), 256, 0, stream>>>(ctx, Wp, Gt);

  // 5) Mt[b] : out[m=co, n=ci] = sum_k Gt[co,k] * WqT[ci,k]  (bf16 path)
  gemm_bt<false><<<dim3(6, 6, 8), 256, 0, stream>>>(Gt, nullptr, Wb + 3 * WE, Mt,
                                                    nullptr, nullptr, WE, 0, WE, 0);

  // 6) out[b] = Qb[b] @ Mt[b]^T + bp  (bf16 A, fp32 out)
  gemm_bt<false><<<dim3(6, 256, 1), 256, 0, stream>>>(Qb, nullptr, Mt, nullptr, out,
                                                      bp, 0, 0, 0, WE);
}

// Round 14
// 298.289 us; speedup vs baseline: 1.0679x; 1.0679x over previous
//
#include <hip/hip_runtime.h>
#include <hip/hip_bf16.h>

// FactorAtt (CoaT) fused pipeline v13, MI355X/gfx950.
// B=8, N=4096, C=768, H=12, D=64.  M_tot = B*N = 32768.
//
// Math: out[b] = q[b] @ M[b] + bp, where
//   Kh = k @ Wk^T (bf16), Vh = v @ Wv^T
//   ctx[b,h,dk,dv] = sum_n softmax_n(Kh)[n,dk] * Vh[n,dv]
//   Gt[b][co][h*64+dk] = sum_dv ctx[b,h,dk,dv] * Wp[co, h*64+dv]
//   Mt[b][co][ci] = sum_kk Gt[b][co][kk] * Wq[kk][ci]
//   out[b][n,co] = sum_ci q[b][n,ci] * Mt[b][co,ci] + bp[co]
// v13 = exact v10 revert (best measured: 299.7us) + merged Wk/Wv cast.
// v12's q-cast split reverted (budget analysis: final-AF32 ~= final-bf16;
// the 24us q-cast was pure loss — my round-12 per-dispatch attribution
// misread rocprof pass-replay duplicates).

typedef __bf16 bf16x8 __attribute__((ext_vector_type(8)));
typedef __bf16 bf16x4 __attribute__((ext_vector_type(4)));
typedef float f32x4 __attribute__((ext_vector_type(4)));

#define GLOAD_LDS16(g, l)                                                        \
  __builtin_amdgcn_global_load_lds(                                              \
      (const __attribute__((address_space(1))) void*)(g),                        \
      (__attribute__((address_space(3))) void*)(l), 16, 0, 0)

__device__ __forceinline__ float bf2f(__hip_bfloat16 h) { return __bfloat162float(h); }

// ---------------------------------------------------------------- casts (weights)
__global__ void cast2_kernel(const float* __restrict__ s0, const float* __restrict__ s1,
                             __bf16* __restrict__ d0, __bf16* __restrict__ d1) {
  const float* src = blockIdx.y == 0 ? s0 : s1;
  __bf16* dst = blockIdx.y == 0 ? d0 : d1;
  const long i = ((long)blockIdx.x * blockDim.x + threadIdx.x) * 4;
  const float4 f = *(const float4*)(src + i);
  bf16x4 u = {(__bf16)f.x, (__bf16)f.y, (__bf16)f.z, (__bf16)f.w};
  *(bf16x4*)(dst + i) = u;
}

// dst[ci][kk] = src[kk][ci]  (768x768, fp32 -> bf16)
__global__ void transpose_cast(const float* __restrict__ src,
                               __bf16* __restrict__ dst) {
  __shared__ float tile[32][33];
  const int bx = blockIdx.x * 32, by = blockIdx.y * 32;
  const int tx = threadIdx.x, ty = threadIdx.y;  // 32 x 8
#pragma unroll
  for (int j = 0; j < 32; j += 8)
    tile[ty + j][tx] = src[(long)(bx + ty + j) * 768 + by + tx];
  __syncthreads();
#pragma unroll
  for (int j = 0; j < 32; j += 8)
    dst[(long)(by + ty + j) * 768 + bx + tx] = (__bf16)tile[tx][ty + j];
}

// ---------------------------------------------------------------- GEMM (B^T form)
// out[m,n] = sum_k A[m,k] * Bt[n,k];  K=768, tiles 128x128, BK=64, 4 waves.
// v7 structure: single-buffered LDS, 2 barriers per K-step, 12 K-steps.
// AF32: A fp32 in global via global_load_lds; LDS A = [128][64] f32,
//   16B-chunk swizzle phys = logical ^ (row&15); cast to bf16 at frag build.
// bf16: LDS A = [128][64] bf16, 8-chunk swizzle phys = logical ^ (row&7).
// A2 != nullptr: z==1 selects A2 (z-stride disabled).
template <bool AF32>
__global__ __launch_bounds__(256, 2)
void gemm_bt(const void* __restrict__ Abase_, const void* __restrict__ A2,
             const __bf16* __restrict__ Btbase,
             __bf16* __restrict__ outBbase,
             float* __restrict__ outF,
             const float* __restrict__ bias,
             long sAz, long sBz, long sOz, long sBbatch) {
  constexpr int K = 768;
  const int tid = threadIdx.x;
  const int lane = tid & 63;
  const int w = tid >> 6;
  const int wr = (w >> 1) * 64;
  const int wc = (w & 1) * 64;

  // bijective XCD-chunked swizzle (m204)
  long flat = ((long)blockIdx.z * gridDim.y + blockIdx.y) * gridDim.x + blockIdx.x;
  const long total = (long)gridDim.x * gridDim.y * gridDim.z;
  if ((total & 7) == 0) {
    flat = (flat & 7) * (total >> 3) + (flat >> 3);
  }
  const int bx = (int)(flat % gridDim.x);
  const long rem = flat / gridDim.x;
  const int by = (int)(rem % gridDim.y);
  const int bz = (int)(rem / gridDim.y);

  const int z = bz;
  const int m0 = by * 128;
  const int n0 = bx * 128;

  const __bf16* Bt = Btbase + (long)z * sBz + (long)(m0 >> 12) * sBbatch;

  __shared__ __align__(16) float AsF[AF32 ? 128 * 64 : 8];   // 32 KB (AF32)
  __shared__ __align__(16) __bf16 AsB[AF32 ? 8 : 128 * 64];  // 16 KB (bf16)
  __shared__ __align__(16) __bf16 Bs[128 * 64];              // 16 KB

  f32x4 acc[4][4] = {};

  // ---- B staging: issue p rows p*32 + w*8 + ro; chunk (lane&7)^ro
  const int ro = lane >> 3;
  const int gck = (lane & 7) ^ ro;
  const __bf16* gB = Bt + (long)(n0 + w * 8 + ro) * K + gck * 8;

  // ---- A staging
  const void* Asel = (A2 != nullptr && z == 1) ? A2 : Abase_;
  const long az = (A2 == nullptr) ? (long)z * sAz : 0;
  const float* gAf = nullptr;
  const __bf16* gAb = nullptr;
  if constexpr (AF32) {
    // 8 issues; issue p rows p*16 + (tid>>4); logical chunk (tid&15)^(tid>>4)
    const int arow = tid >> 4;
    const int ach = (tid & 15) ^ arow;
    gAf = (const float*)Asel + az + (long)(m0 + arow) * K + ach * 4;
  } else {
    gAb = (const __bf16*)Asel + az + (long)(m0 + w * 8 + ro) * K + gck * 8;
  }

  const int rsel = lane & 15;
  const int r7 = rsel & 7;
  const int cseg = lane >> 4;  // 0..3

  for (int k0 = 0; k0 < K; k0 += 64) {
    if constexpr (AF32) {
#pragma unroll
      for (int p = 0; p < 8; ++p)
        GLOAD_LDS16(gAf + k0 + (long)p * 16 * K, &AsF[p * 1024 + w * 256]);
#pragma unroll
      for (int p = 0; p < 4; ++p)
        GLOAD_LDS16(gB + k0 + (long)p * 32 * K, &Bs[(p * 32 + w * 8) * 64]);
    } else {
#pragma unroll
      for (int p = 0; p < 4; ++p) {
        GLOAD_LDS16(gAb + k0 + (long)p * 32 * K, &AsB[(p * 32 + w * 8) * 64]);
        GLOAD_LDS16(gB + k0 + (long)p * 32 * K, &Bs[(p * 32 + w * 8) * 64]);
      }
    }
    __syncthreads();

#pragma unroll
    for (int kk = 0; kk < 2; ++kk) {
      bf16x8 af[4], bfr[4];
#pragma unroll
      for (int i = 0; i < 4; ++i) {
        const int rowa = wr + i * 16 + rsel;   // rowa & 15 == rsel
        const int rowb = wc + i * 16 + rsel;
        if constexpr (AF32) {
          const int c0 = kk * 8 + cseg * 2;    // logical f32-chunk (even)
          const f32x4 lo = *(const f32x4*)&AsF[rowa * 64 + ((c0 ^ rsel) << 2)];
          const f32x4 hi = *(const f32x4*)&AsF[rowa * 64 + (((c0 + 1) ^ rsel) << 2)];
          bf16x8 a = {(__bf16)lo[0], (__bf16)lo[1], (__bf16)lo[2], (__bf16)lo[3],
                      (__bf16)hi[0], (__bf16)hi[1], (__bf16)hi[2], (__bf16)hi[3]};
          af[i] = a;
        } else {
          const int ckl = kk * 4 + cseg;       // logical bf16-chunk
          af[i] = *(const bf16x8*)&AsB[rowa * 64 + ((ckl ^ r7) << 3)];
        }
        const int ckl = kk * 4 + cseg;
        bfr[i] = *(const bf16x8*)&Bs[rowb * 64 + ((ckl ^ r7) << 3)];
      }
#pragma unroll
      for (int i = 0; i < 4; ++i)
#pragma unroll
        for (int j = 0; j < 4; ++j)
          acc[i][j] = __builtin_amdgcn_mfma_f32_16x16x32_bf16(af[i], bfr[j], acc[i][j], 0, 0, 0);
    }
    __syncthreads();
  }

  // C/D layout (m89): col = lane&15, row = (lane>>4)*4 + r
  const int r0 = (lane >> 4) * 4;
  if (outF == nullptr) {
    __bf16* outp = outBbase + (long)z * sOz;
#pragma unroll
    for (int i = 0; i < 4; ++i) {
      const int row = m0 + wr + i * 16 + r0;
#pragma unroll
      for (int j = 0; j < 4; ++j) {
        const int col = n0 + wc + j * 16 + rsel;
#pragma unroll
        for (int r = 0; r < 4; ++r)
          outp[(long)(row + r) * 768 + col] = (__bf16)acc[i][j][r];
      }
    }
  } else {
#pragma unroll
    for (int i = 0; i < 4; ++i) {
      const int row = m0 + wr + i * 16 + r0;
#pragma unroll
      for (int j = 0; j < 4; ++j) {
        const int col = n0 + wc + j * 16 + rsel;
        const float bv = bias[col];
#pragma unroll
        for (int r = 0; r < 4; ++r)
          outF[(long)(row + r) * 768 + col] = acc[i][j][r] + bv;
      }
    }
  }
}

// ---------------------------------------------------------------- ctx partials
// Per (b,h), n-chunk of 512: U[dk,dv] += exp(Kh[n,dk]) * Vh[n,dv]; S[dk] += exp.
__global__ __launch_bounds__(256)
void ctx_partial(const __bf16* __restrict__ Kh,
                 const __bf16* __restrict__ Vh,
                 float* __restrict__ Upart, float* __restrict__ Spart) {
  const int bh = blockIdx.y, chunk = blockIdx.x;
  const int b = bh / 12, h = bh % 12;
  const int t = threadIdx.x;
  const int tdk = (t & 15) * 4, tdv = (t >> 4) * 4;
  const int sr = t >> 3, sc = (t & 7) * 8;
  __shared__ float ek[32][64];
  __shared__ float vv[32][64];
  f32x4 U[4] = {};
  float sacc = 0.f;
  const long base = ((long)b * 4096 + (long)chunk * 512) * 768 + h * 64;
#pragma unroll 1
  for (int it = 0; it < 16; ++it) {
    const long roff = base + (long)(it * 32 + sr) * 768 + sc;
    const bf16x8 kb = *(const bf16x8*)(Kh + roff);
    const bf16x8 vb = *(const bf16x8*)(Vh + roff);
    __syncthreads();
#pragma unroll
    for (int j = 0; j < 8; ++j) {
      ek[sr][sc + j] = __expf((float)kb[j]);
      vv[sr][sc + j] = (float)vb[j];
    }
    __syncthreads();
#pragma unroll 4
    for (int r = 0; r < 32; ++r) {
      const f32x4 a = *(const f32x4*)&ek[r][tdk];
      const f32x4 vx = *(const f32x4*)&vv[r][tdv];
      U[0] += a[0] * vx;
      U[1] += a[1] * vx;
      U[2] += a[2] * vx;
      U[3] += a[3] * vx;
    }
    if (t < 64) {
#pragma unroll 4
      for (int r = 0; r < 32; ++r) sacc += ek[r][t];
    }
  }
  float* Ub = Upart + (long)(bh * 8 + chunk) * 4096;
#pragma unroll
  for (int i = 0; i < 4; ++i) *(f32x4*)&Ub[(tdk + i) * 64 + tdv] = U[i];
  if (t < 64) Spart[(long)(bh * 8 + chunk) * 64 + t] = sacc;
}

__global__ __launch_bounds__(256)
void ctx_reduce(const float* __restrict__ Upart, const float* __restrict__ Spart,
                float* __restrict__ ctx) {
  const int bh = blockIdx.x;
  const int t = threadIdx.x;
  const int tdk = (t & 15) * 4, tdv = (t >> 4) * 4;
  __shared__ float S[64];
  if (t < 64) {
    float s = 0.f;
#pragma unroll
    for (int c = 0; c < 8; ++c) s += Spart[(long)(bh * 8 + c) * 64 + t];
    S[t] = s;
  }
  __syncthreads();
#pragma unroll
  for (int i = 0; i < 4; ++i) {
    const int dk = tdk + i;
    f32x4 u = {};
#pragma unroll
    for (int c = 0; c < 8; ++c)
      u += *(const f32x4*)&Upart[(long)(bh * 8 + c) * 4096 + dk * 64 + tdv];
    u *= (1.f / S[dk]);
    *(f32x4*)&ctx[(long)bh * 4096 + dk * 64 + tdv] = u;
  }
}

// ---------------------------------------------------------------- G matrix
// Gt[b][co][h*64+dk] = sum_dv ctx[b,h,dk,dv] * Wp[co, h*64+dv]   (bf16 out)
__global__ __launch_bounds__(256, 2)
void gstack(const float* __restrict__ ctx, const float* __restrict__ Wp,
            __bf16* __restrict__ Gt) {
  const int cc = blockIdx.x, h = blockIdx.y, b = blockIdx.z;
  const int t = threadIdx.x, lane = t & 63, w = t >> 6;
  const int co0 = cc * 192;
  __shared__ __align__(16) float wf[192 * 64];  // 48 KB

#pragma unroll
  for (int i = 0; i < 12; ++i) {
    const int flat = i * 256 + t;
    const int r = flat >> 4, c4 = flat & 15;
    const f32x4 vsrc = *(const f32x4*)&Wp[(long)(co0 + r) * 768 + h * 64 + c4 * 4];
    *(f32x4*)&wf[r * 64 + c4 * 4] = vsrc;
  }

  f32x4 cx[16];
  const float* crow = ctx + ((long)(b * 12 + h) * 64 + lane) * 64;
#pragma unroll
  for (int j = 0; j < 16; ++j) cx[j] = *(const f32x4*)&crow[j * 4];

  __syncthreads();

  __bf16* gout = Gt + ((long)(b * 768 + co0 + w * 48) * 768) + h * 64 + lane;
  for (int co = 0; co < 48; ++co) {
    const float* wrow = &wf[(w * 48 + co) * 64];
    f32x4 acc = {};
#pragma unroll
    for (int j = 0; j < 16; ++j) acc += cx[j] * *(const f32x4*)&wrow[j * 4];
    const float s = acc[0] + acc[1] + acc[2] + acc[3];
    gout[(long)co * 768] = (__bf16)s;
  }
}

// ---------------------------------------------------------------- launch
extern "C" void kernel_launch(void* const* d_in, const int* in_sizes, int n_in,
                              void* d_out, int out_size, void* d_ws, size_t ws_size,
                              hipStream_t stream) {
  (void)in_sizes; (void)n_in; (void)out_size; (void)ws_size;
  const float* q = (const float*)d_in[0];
  const float* k = (const float*)d_in[1];
  const float* v = (const float*)d_in[2];
  const float* Wq = (const float*)d_in[3];
  const float* Wk = (const float*)d_in[4];
  const float* Wv = (const float*)d_in[5];
  const float* Wp = (const float*)d_in[6];
  const float* bp = (const float*)d_in[7];
  float* out = (float*)d_out;

  const long XE = 32768L * 768L;
  const long WE = 768L * 768L;

  char* ws = (char*)d_ws;
  __bf16* Khb = (__bf16*)ws;                             // XE bf16
  __bf16* Vhb = Khb + XE;                                // XE bf16
  __bf16* Wb = Vhb + XE;                                 // 4*WE bf16: Wk,Wv,(spare),WqT
  __bf16* Gt = Wb + 4 * WE;                              // 8*WE bf16
  __bf16* Mt = Gt + 8 * WE;                              // 8*WE bf16
  float* Upart = (float*)(Mt + 8 * WE);                  // 96*8*4096 f32
  float* Spart = Upart + 96L * 8 * 4096;                 // 96*8*64 f32
  float* ctx = Spart + 96L * 8 * 64;                     // 96*4096 f32

  // 1) weight casts (merged) + WqT
  cast2_kernel<<<dim3(576, 2), 256, 0, stream>>>(Wk, Wv, Wb + 0 * WE, Wb + 1 * WE);
  transpose_cast<<<dim3(24, 24), dim3(32, 8), 0, stream>>>(Wq, Wb + 3 * WE);  // WqT

  // 2) K/V projections (z=2, fp32 A direct): z=0 Kh = k@Wk^T, z=1 Vh = v@Wv^T
  gemm_bt<true><<<dim3(6, 256, 2), 256, 0, stream>>>(k, v, Wb, Khb, nullptr,
                                                     nullptr, 0, WE, XE, 0);

  // 3) softmax-weighted context
  ctx_partial<<<dim3(8, 96), 256, 0, stream>>>(Khb, Vhb, Upart, Spart);
  ctx_reduce<<<96, 256, 0, stream>>>(Upart, Spart, ctx);

  // 4) Gt[b] = (ctx @ Wp-blocks)^T  (fp32 Wp direct)
  gstack<<<dim3(4, 12, 8), 256, 0, stream>>>(ctx, Wp, Gt);

  // 5) Mt[b] : out[m=co, n=ci] = sum_k Gt[co,k] * WqT[ci,k]  (bf16 path)
  gemm_bt<false><<<dim3(6, 6, 8), 256, 0, stream>>>(Gt, nullptr, Wb + 3 * WE, Mt,
                                                    nullptr, nullptr, WE, 0, WE, 0);

  // 6) out[b] = q[b] @ Mt[b]^T + bp  (fp32 A direct, fp32 out)
  gemm_bt<true><<<dim3(6, 256, 1), 256, 0, stream>>>(q, nullptr, Mt, nullptr, out,
                                                     bp, 0, 0, 0, WE);
}

// Round 15
// 296.848 us; speedup vs baseline: 1.0731x; 1.0049x over previous
//
#include <hip/hip_runtime.h>
#include <hip/hip_bf16.h>

// FactorAtt (CoaT) fused pipeline v14, MI355X/gfx950.
// B=8, N=4096, C=768, H=12, D=64.  M_tot = B*N = 32768.
//
// Math: out[b] = q[b] @ M[b] + bp, where
//   Kh = k @ Wk^T (bf16), Vh = v @ Wv^T
//   ctx[b,h,dk,dv] = sum_n softmax_n(Kh)[n,dk] * Vh[n,dv]
//   Gt[b][co][h*64+dk] = sum_dv ctx[b,h,dk,dv] * Wp[co, h*64+dv]
//   Mt[b][co][ci] = sum_kk Gt[b][co][kk] * Wq[kk][ci]
//   out[b][n,co] = sum_ci q[b][n,ci] * Mt[b][co,ci] + bp[co]
// v14 = v13 (best: 298.3us) + all weight-prep (Wk cast, Wv cast, Wq
// transpose-cast) merged into ONE dispatch (launch-overhead removal only).
// Config is the measured optimum of the 14-round search:
//  - gemm: v7 structure (BK=64, single-buffer, 2 barriers/K-step, XOR chunk
//    swizzle both-sides, 0 bank conflicts) — beat 5 deep-pipeline variants.
//  - proj+final: AF32 fused A (fp32 direct via global_load_lds, cvt at frag).
//  - ctx path: 32-row-tile partial + reduce (HBM-ceiling-bound).

typedef __bf16 bf16x8 __attribute__((ext_vector_type(8)));
typedef __bf16 bf16x4 __attribute__((ext_vector_type(4)));
typedef float f32x4 __attribute__((ext_vector_type(4)));

#define GLOAD_LDS16(g, l)                                                        \
  __builtin_amdgcn_global_load_lds(                                              \
      (const __attribute__((address_space(1))) void*)(g),                        \
      (__attribute__((address_space(3))) void*)(l), 16, 0, 0)

__device__ __forceinline__ float bf2f(__hip_bfloat16 h) { return __bfloat162float(h); }

// ---------------------------------------------------------------- weight prep
// One dispatch, grid (576, 3):
//   y=0: Wk -> Wb[0] (bf16 cast), y=1: Wv -> Wb[1], y=2: Wq^T -> Wb[3].
__global__ void weight_prep(const float* __restrict__ Wk, const float* __restrict__ Wv,
                            const float* __restrict__ Wq,
                            __bf16* __restrict__ d0, __bf16* __restrict__ d1,
                            __bf16* __restrict__ d3) {
  if (blockIdx.y < 2) {
    const float* src = blockIdx.y == 0 ? Wk : Wv;
    __bf16* dst = blockIdx.y == 0 ? d0 : d1;
    const long i = ((long)blockIdx.x * blockDim.x + threadIdx.x) * 4;
    const float4 f = *(const float4*)(src + i);
    bf16x4 u = {(__bf16)f.x, (__bf16)f.y, (__bf16)f.z, (__bf16)f.w};
    *(bf16x4*)(dst + i) = u;
  } else {
    // transpose-cast: 24x24 tile grid packed into blockIdx.x = ty*24+tx
    __shared__ float tile[32][33];
    const int bxi = blockIdx.x % 24, byi = blockIdx.x / 24;
    const int bx = bxi * 32, by = byi * 32;      // bx: kk base, by: ci base
    const int tx = threadIdx.x & 31, ty = threadIdx.x >> 5;  // 32 x 8
#pragma unroll
    for (int j = 0; j < 32; j += 8)
      tile[ty + j][tx] = Wq[(long)(bx + ty + j) * 768 + by + tx];
    __syncthreads();
#pragma unroll
    for (int j = 0; j < 32; j += 8)
      d3[(long)(by + ty + j) * 768 + bx + tx] = (__bf16)tile[tx][ty + j];
  }
}

// ---------------------------------------------------------------- GEMM (B^T form)
// out[m,n] = sum_k A[m,k] * Bt[n,k];  K=768, tiles 128x128, BK=64, 4 waves.
// v7 structure: single-buffered LDS, 2 barriers per K-step, 12 K-steps.
// AF32: A fp32 in global via global_load_lds; LDS A = [128][64] f32,
//   16B-chunk swizzle phys = logical ^ (row&15); cast to bf16 at frag build.
// bf16: LDS A = [128][64] bf16, 8-chunk swizzle phys = logical ^ (row&7).
// A2 != nullptr: z==1 selects A2 (z-stride disabled).
template <bool AF32>
__global__ __launch_bounds__(256, 2)
void gemm_bt(const void* __restrict__ Abase_, const void* __restrict__ A2,
             const __bf16* __restrict__ Btbase,
             __bf16* __restrict__ outBbase,
             float* __restrict__ outF,
             const float* __restrict__ bias,
             long sAz, long sBz, long sOz, long sBbatch) {
  constexpr int K = 768;
  const int tid = threadIdx.x;
  const int lane = tid & 63;
  const int w = tid >> 6;
  const int wr = (w >> 1) * 64;
  const int wc = (w & 1) * 64;

  // bijective XCD-chunked swizzle (m204)
  long flat = ((long)blockIdx.z * gridDim.y + blockIdx.y) * gridDim.x + blockIdx.x;
  const long total = (long)gridDim.x * gridDim.y * gridDim.z;
  if ((total & 7) == 0) {
    flat = (flat & 7) * (total >> 3) + (flat >> 3);
  }
  const int bx = (int)(flat % gridDim.x);
  const long rem = flat / gridDim.x;
  const int by = (int)(rem % gridDim.y);
  const int bz = (int)(rem / gridDim.y);

  const int z = bz;
  const int m0 = by * 128;
  const int n0 = bx * 128;

  const __bf16* Bt = Btbase + (long)z * sBz + (long)(m0 >> 12) * sBbatch;

  __shared__ __align__(16) float AsF[AF32 ? 128 * 64 : 8];   // 32 KB (AF32)
  __shared__ __align__(16) __bf16 AsB[AF32 ? 8 : 128 * 64];  // 16 KB (bf16)
  __shared__ __align__(16) __bf16 Bs[128 * 64];              // 16 KB

  f32x4 acc[4][4] = {};

  // ---- B staging: issue p rows p*32 + w*8 + ro; chunk (lane&7)^ro
  const int ro = lane >> 3;
  const int gck = (lane & 7) ^ ro;
  const __bf16* gB = Bt + (long)(n0 + w * 8 + ro) * K + gck * 8;

  // ---- A staging
  const void* Asel = (A2 != nullptr && z == 1) ? A2 : Abase_;
  const long az = (A2 == nullptr) ? (long)z * sAz : 0;
  const float* gAf = nullptr;
  const __bf16* gAb = nullptr;
  if constexpr (AF32) {
    // 8 issues; issue p rows p*16 + (tid>>4); logical chunk (tid&15)^(tid>>4)
    const int arow = tid >> 4;
    const int ach = (tid & 15) ^ arow;
    gAf = (const float*)Asel + az + (long)(m0 + arow) * K + ach * 4;
  } else {
    gAb = (const __bf16*)Asel + az + (long)(m0 + w * 8 + ro) * K + gck * 8;
  }

  const int rsel = lane & 15;
  const int r7 = rsel & 7;
  const int cseg = lane >> 4;  // 0..3

  for (int k0 = 0; k0 < K; k0 += 64) {
    if constexpr (AF32) {
#pragma unroll
      for (int p = 0; p < 8; ++p)
        GLOAD_LDS16(gAf + k0 + (long)p * 16 * K, &AsF[p * 1024 + w * 256]);
#pragma unroll
      for (int p = 0; p < 4; ++p)
        GLOAD_LDS16(gB + k0 + (long)p * 32 * K, &Bs[(p * 32 + w * 8) * 64]);
    } else {
#pragma unroll
      for (int p = 0; p < 4; ++p) {
        GLOAD_LDS16(gAb + k0 + (long)p * 32 * K, &AsB[(p * 32 + w * 8) * 64]);
        GLOAD_LDS16(gB + k0 + (long)p * 32 * K, &Bs[(p * 32 + w * 8) * 64]);
      }
    }
    __syncthreads();

#pragma unroll
    for (int kk = 0; kk < 2; ++kk) {
      bf16x8 af[4], bfr[4];
#pragma unroll
      for (int i = 0; i < 4; ++i) {
        const int rowa = wr + i * 16 + rsel;   // rowa & 15 == rsel
        const int rowb = wc + i * 16 + rsel;
        if constexpr (AF32) {
          const int c0 = kk * 8 + cseg * 2;    // logical f32-chunk (even)
          const f32x4 lo = *(const f32x4*)&AsF[rowa * 64 + ((c0 ^ rsel) << 2)];
          const f32x4 hi = *(const f32x4*)&AsF[rowa * 64 + (((c0 + 1) ^ rsel) << 2)];
          bf16x8 a = {(__bf16)lo[0], (__bf16)lo[1], (__bf16)lo[2], (__bf16)lo[3],
                      (__bf16)hi[0], (__bf16)hi[1], (__bf16)hi[2], (__bf16)hi[3]};
          af[i] = a;
        } else {
          const int ckl = kk * 4 + cseg;       // logical bf16-chunk
          af[i] = *(const bf16x8*)&AsB[rowa * 64 + ((ckl ^ r7) << 3)];
        }
        const int ckl = kk * 4 + cseg;
        bfr[i] = *(const bf16x8*)&Bs[rowb * 64 + ((ckl ^ r7) << 3)];
      }
#pragma unroll
      for (int i = 0; i < 4; ++i)
#pragma unroll
        for (int j = 0; j < 4; ++j)
          acc[i][j] = __builtin_amdgcn_mfma_f32_16x16x32_bf16(af[i], bfr[j], acc[i][j], 0, 0, 0);
    }
    __syncthreads();
  }

  // C/D layout (m89): col = lane&15, row = (lane>>4)*4 + r
  const int r0 = (lane >> 4) * 4;
  if (outF == nullptr) {
    __bf16* outp = outBbase + (long)z * sOz;
#pragma unroll
    for (int i = 0; i < 4; ++i) {
      const int row = m0 + wr + i * 16 + r0;
#pragma unroll
      for (int j = 0; j < 4; ++j) {
        const int col = n0 + wc + j * 16 + rsel;
#pragma unroll
        for (int r = 0; r < 4; ++r)
          outp[(long)(row + r) * 768 + col] = (__bf16)acc[i][j][r];
      }
    }
  } else {
#pragma unroll
    for (int i = 0; i < 4; ++i) {
      const int row = m0 + wr + i * 16 + r0;
#pragma unroll
      for (int j = 0; j < 4; ++j) {
        const int col = n0 + wc + j * 16 + rsel;
        const float bv = bias[col];
#pragma unroll
        for (int r = 0; r < 4; ++r)
          outF[(long)(row + r) * 768 + col] = acc[i][j][r] + bv;
      }
    }
  }
}

// ---------------------------------------------------------------- ctx partials
// Per (b,h), n-chunk of 512: U[dk,dv] += exp(Kh[n,dk]) * Vh[n,dv]; S[dk] += exp.
__global__ __launch_bounds__(256)
void ctx_partial(const __bf16* __restrict__ Kh,
                 const __bf16* __restrict__ Vh,
                 float* __restrict__ Upart, float* __restrict__ Spart) {
  const int bh = blockIdx.y, chunk = blockIdx.x;
  const int b = bh / 12, h = bh % 12;
  const int t = threadIdx.x;
  const int tdk = (t & 15) * 4, tdv = (t >> 4) * 4;
  const int sr = t >> 3, sc = (t & 7) * 8;
  __shared__ float ek[32][64];
  __shared__ float vv[32][64];
  f32x4 U[4] = {};
  float sacc = 0.f;
  const long base = ((long)b * 4096 + (long)chunk * 512) * 768 + h * 64;
#pragma unroll 1
  for (int it = 0; it < 16; ++it) {
    const long roff = base + (long)(it * 32 + sr) * 768 + sc;
    const bf16x8 kb = *(const bf16x8*)(Kh + roff);
    const bf16x8 vb = *(const bf16x8*)(Vh + roff);
    __syncthreads();
#pragma unroll
    for (int j = 0; j < 8; ++j) {
      ek[sr][sc + j] = __expf((float)kb[j]);
      vv[sr][sc + j] = (float)vb[j];
    }
    __syncthreads();
#pragma unroll 4
    for (int r = 0; r < 32; ++r) {
      const f32x4 a = *(const f32x4*)&ek[r][tdk];
      const f32x4 vx = *(const f32x4*)&vv[r][tdv];
      U[0] += a[0] * vx;
      U[1] += a[1] * vx;
      U[2] += a[2] * vx;
      U[3] += a[3] * vx;
    }
    if (t < 64) {
#pragma unroll 4
      for (int r = 0; r < 32; ++r) sacc += ek[r][t];
    }
  }
  float* Ub = Upart + (long)(bh * 8 + chunk) * 4096;
#pragma unroll
  for (int i = 0; i < 4; ++i) *(f32x4*)&Ub[(tdk + i) * 64 + tdv] = U[i];
  if (t < 64) Spart[(long)(bh * 8 + chunk) * 64 + t] = sacc;
}

__global__ __launch_bounds__(256)
void ctx_reduce(const float* __restrict__ Upart, const float* __restrict__ Spart,
                float* __restrict__ ctx) {
  const int bh = blockIdx.x;
  const int t = threadIdx.x;
  const int tdk = (t & 15) * 4, tdv = (t >> 4) * 4;
  __shared__ float S[64];
  if (t < 64) {
    float s = 0.f;
#pragma unroll
    for (int c = 0; c < 8; ++c) s += Spart[(long)(bh * 8 + c) * 64 + t];
    S[t] = s;
  }
  __syncthreads();
#pragma unroll
  for (int i = 0; i < 4; ++i) {
    const int dk = tdk + i;
    f32x4 u = {};
#pragma unroll
    for (int c = 0; c < 8; ++c)
      u += *(const f32x4*)&Upart[(long)(bh * 8 + c) * 4096 + dk * 64 + tdv];
    u *= (1.f / S[dk]);
    *(f32x4*)&ctx[(long)bh * 4096 + dk * 64 + tdv] = u;
  }
}

// ---------------------------------------------------------------- G matrix
// Gt[b][co][h*64+dk] = sum_dv ctx[b,h,dk,dv] * Wp[co, h*64+dv]   (bf16 out)
__global__ __launch_bounds__(256, 2)
void gstack(const float* __restrict__ ctx, const float* __restrict__ Wp,
            __bf16* __restrict__ Gt) {
  const int cc = blockIdx.x, h = blockIdx.y, b = blockIdx.z;
  const int t = threadIdx.x, lane = t & 63, w = t >> 6;
  const int co0 = cc * 192;
  __shared__ __align__(16) float wf[192 * 64];  // 48 KB

#pragma unroll
  for (int i = 0; i < 12; ++i) {
    const int flat = i * 256 + t;
    const int r = flat >> 4, c4 = flat & 15;
    const f32x4 vsrc = *(const f32x4*)&Wp[(long)(co0 + r) * 768 + h * 64 + c4 * 4];
    *(f32x4*)&wf[r * 64 + c4 * 4] = vsrc;
  }

  f32x4 cx[16];
  const float* crow = ctx + ((long)(b * 12 + h) * 64 + lane) * 64;
#pragma unroll
  for (int j = 0; j < 16; ++j) cx[j] = *(const f32x4*)&crow[j * 4];

  __syncthreads();

  __bf16* gout = Gt + ((long)(b * 768 + co0 + w * 48) * 768) + h * 64 + lane;
  for (int co = 0; co < 48; ++co) {
    const float* wrow = &wf[(w * 48 + co) * 64];
    f32x4 acc = {};
#pragma unroll
    for (int j = 0; j < 16; ++j) acc += cx[j] * *(const f32x4*)&wrow[j * 4];
    const float s = acc[0] + acc[1] + acc[2] + acc[3];
    gout[(long)co * 768] = (__bf16)s;
  }
}

// ---------------------------------------------------------------- launch
extern "C" void kernel_launch(void* const* d_in, const int* in_sizes, int n_in,
                              void* d_out, int out_size, void* d_ws, size_t ws_size,
                              hipStream_t stream) {
  (void)in_sizes; (void)n_in; (void)out_size; (void)ws_size;
  const float* q = (const float*)d_in[0];
  const float* k = (const float*)d_in[1];
  const float* v = (const float*)d_in[2];
  const float* Wq = (const float*)d_in[3];
  const float* Wk = (const float*)d_in[4];
  const float* Wv = (const float*)d_in[5];
  const float* Wp = (const float*)d_in[6];
  const float* bp = (const float*)d_in[7];
  float* out = (float*)d_out;

  const long XE = 32768L * 768L;
  const long WE = 768L * 768L;

  char* ws = (char*)d_ws;
  __bf16* Khb = (__bf16*)ws;                             // XE bf16
  __bf16* Vhb = Khb + XE;                                // XE bf16
  __bf16* Wb = Vhb + XE;                                 // 4*WE bf16: Wk,Wv,(spare),WqT
  __bf16* Gt = Wb + 4 * WE;                              // 8*WE bf16
  __bf16* Mt = Gt + 8 * WE;                              // 8*WE bf16
  float* Upart = (float*)(Mt + 8 * WE);                  // 96*8*4096 f32
  float* Spart = Upart + 96L * 8 * 4096;                 // 96*8*64 f32
  float* ctx = Spart + 96L * 8 * 64;                     // 96*4096 f32

  // 1) all weight prep in one dispatch (Wk cast, Wv cast, WqT transpose-cast)
  weight_prep<<<dim3(576, 3), 256, 0, stream>>>(Wk, Wv, Wq,
                                                Wb + 0 * WE, Wb + 1 * WE, Wb + 3 * WE);

  // 2) K/V projections (z=2, fp32 A direct): z=0 Kh = k@Wk^T, z=1 Vh = v@Wv^T
  gemm_bt<true><<<dim3(6, 256, 2), 256, 0, stream>>>(k, v, Wb, Khb, nullptr,
                                                     nullptr, 0, WE, XE, 0);

  // 3) softmax-weighted context
  ctx_partial<<<dim3(8, 96), 256, 0, stream>>>(Khb, Vhb, Upart, Spart);
  ctx_reduce<<<96, 256, 0, stream>>>(Upart, Spart, ctx);

  // 4) Gt[b] = (ctx @ Wp-blocks)^T  (fp32 Wp direct)
  gstack<<<dim3(4, 12, 8), 256, 0, stream>>>(ctx, Wp, Gt);

  // 5) Mt[b] : out[m=co, n=ci] = sum_k Gt[co,k] * WqT[ci,k]  (bf16 path)
  gemm_bt<false><<<dim3(6, 6, 8), 256, 0, stream>>>(Gt, nullptr, Wb + 3 * WE, Mt,
                                                    nullptr, nullptr, WE, 0, WE, 0);

  // 6) out[b] = q[b] @ Mt[b]^T + bp  (fp32 A direct, fp32 out)
  gemm_bt<true><<<dim3(6, 256, 1), 256, 0, stream>>>(q, nullptr, Mt, nullptr, out,
                                                     bp, 0, 0, 0, WE);
}